// Round 9
// baseline (45.001 us; speedup 1.0000x reference)
//
#include <hip/hip_runtime.h>

constexpr int NPTS  = 1024;   // points per batch
constexpr int NT    = 21;     // targets per batch
constexpr int KSEL  = 64;     // top-k
constexpr int BLOCK = 256;    // 4 waves per block
constexpr int PPL   = 16;     // points per lane (1024 / 64)
constexpr int NXCD  = 8;
constexpr int WPB   = 11;     // waves per b: 10 waves x 2 targets + 1 wave x 1 target

typedef float f32x4 __attribute__((ext_vector_type(4)));

__device__ __forceinline__ unsigned key_of(float d) {
    // monotone float->uint transform (total order matching float <)
    unsigned u = __float_as_uint(d);
    return (u & 0x80000000u) ? ~u : (u | 0x80000000u);
}

__device__ __forceinline__ unsigned mbcnt64(unsigned long long m) {
    unsigned lo = __builtin_amdgcn_mbcnt_lo((unsigned)m, 0u);
    return __builtin_amdgcn_mbcnt_hi((unsigned)(m >> 32), lo);
}

// ---- threshold-form exact select state (bit-identical logic to round 8) ----
struct SelState {
    unsigned lo, below, want, cls, Tsel, kth;
    int s;
    bool early, done;
};

__device__ __forceinline__ void compute_keys(
    const float* __restrict__ base, float t0, float t1, float t2, float dt,
    int lane, unsigned* key)
{
    #pragma unroll
    for (int i = 0; i < PPL; ++i) {
        const float* pp = base + 3 * (64 * i + lane);
        const float p0 = pp[0], p1 = pp[1], p2 = pp[2];
        const float d  = dt + (p0 * p0 + p1 * p1 + p2 * p2)
                            - 2.0f * (t0 * p0 + t1 * p1 + t2 * p2);
        key[i] = key_of(d);
    }
}

__device__ __forceinline__ void sel_init(SelState& st, const unsigned* key) {
    unsigned kand = key[0], kor = key[0];
    #pragma unroll
    for (int i = 1; i < PPL; ++i) { kand &= key[i]; kor |= key[i]; }
    #pragma unroll
    for (int off = 32; off > 0; off >>= 1) {
        kand &= (unsigned)__shfl_xor((int)kand, off, 64);
        kor  |= (unsigned)__shfl_xor((int)kor,  off, 64);
    }
    const unsigned dis = kor & ~kand;
    st.below = 0; st.want = KSEL; st.cls = NPTS;
    st.early = false; st.done = false; st.lo = 0; st.Tsel = 0; st.kth = 0; st.s = 0;
    if (dis == 0u) { st.kth = kand; st.done = true; }
    else {
        const int hb = 31 - __builtin_clz(dis);
        st.lo = (hb == 31) ? 0u : (kand & (~0u << (hb + 1)));
        st.s  = hb;
    }
}

__device__ __forceinline__ void sel_step(SelState& st, const unsigned* key) {
    if (st.done) return;                         // wave-uniform skip
    const unsigned mid = st.lo | (1u << st.s);
    unsigned cnt = 0;
    #pragma unroll
    for (int i = 0; i < PPL; ++i) cnt += (key[i] < mid) ? 1u : 0u;
    unsigned c = 0;
    #pragma unroll
    for (int j = 0; j < 5; ++j)
        c += (unsigned)__popcll(__ballot((cnt >> j) & 1u)) << j;
    const unsigned t = c - st.below;             // size of class-0 = [lo, mid)
    if (st.want <= t) { st.cls = t; }
    else { st.want -= t; st.below = c; st.lo = mid; st.cls -= t; }
    if (st.cls == st.want) { st.early = true; st.Tsel = st.lo + (1u << st.s); st.done = true; }
    else if (--st.s < 0)   { st.kth = st.lo; st.done = true; }
}

__device__ __forceinline__ unsigned sel_flags(const SelState& st, const unsigned* key) {
    unsigned selmask = 0;                        // bit i => point (64*i + lane)
    if (st.early) {
        #pragma unroll
        for (int i = 0; i < PPL; ++i)
            if (key[i] < st.Tsel) selmask |= (1u << i);
    } else {
        unsigned run_tot = 0;                    // stable lowest-index tie-break
        #pragma unroll
        for (int i = 0; i < PPL; ++i) {
            const bool eq = (key[i] == st.kth);
            const unsigned long long bal = __ballot(eq);
            const bool sel_eq = eq && (run_tot + mbcnt64(bal)) < st.want;
            if (key[i] < st.kth || sel_eq) selmask |= (1u << i);
            run_tot += (unsigned)__popcll(bal);
        }
    }
    return selmask;
}

// masked coalesced store of one 16B chunk m = 64*j + lane (round-5 mapping)
__device__ __forceinline__ void store_chunk(
    const f32x4* __restrict__ src4, f32x4* __restrict__ dst4,
    unsigned selmask, int lane, int j)
{
    const int      m  = 64 * j + lane;
    const f32x4    g  = src4[m];
    const unsigned e0 = 4u * (unsigned)m;
    const unsigned q  = e0 / 3u;
    const unsigned u  = e0 - 3u * q;
    const unsigned sm0 = (unsigned)__shfl((int)selmask, (int)(q & 63u), 64);
    const unsigned sm1 = (unsigned)__shfl((int)selmask, (int)((q + 1u) & 63u), 64);
    const unsigned b0  = (sm0 >> (q >> 6)) & 1u;
    const unsigned b1  = (sm1 >> ((q + 1u) >> 6)) & 1u;
    f32x4 v;
    v.x = b0                    ? g.x : 0.0f;
    v.y = ((u == 2u) ? b1 : b0) ? g.y : 0.0f;
    v.z = ((u == 0u) ? b0 : b1) ? g.z : 0.0f;
    v.w = b1                    ? g.w : 0.0f;
    dst4[m] = v;
}

__global__ __launch_bounds__(BLOCK) void knn_mask_paired_kernel(
    const float* __restrict__ pc,   // (B, 1024, 3)
    const float* __restrict__ tgt,  // (B, 21, 3)
    float* __restrict__ out,        // (B, 21, 1024, 3)
    int B)
{
    const int wave = threadIdx.x >> 6;
    const int lane = threadIdx.x & 63;
    // bijective XCD swizzle when grid is divisible by 8
    int sbid = blockIdx.x;
    if ((gridDim.x & (NXCD - 1)) == 0) {
        const int cpx = gridDim.x / NXCD;
        sbid = ((int)blockIdx.x % NXCD) * cpx + (int)blockIdx.x / NXCD;
    }
    const int gw = sbid * 4 + wave;
    if (gw >= B * WPB) return;           // wave-uniform
    const int b   = gw / WPB;
    const int w   = gw % WPB;
    const int tq0 = 2 * w;
    const bool has2 = (w < 10);          // wave 10 owns target 20 alone

    const float* base = pc + (size_t)b * (NPTS * 3);
    const f32x4* src4 = reinterpret_cast<const f32x4*>(base);

    // ---- keys for target 0 (and target 1: its 48 loads issue here and land
    // under select0's dependent chain) ----
    const float* tpA = tgt + ((size_t)b * NT + tq0) * 3;
    const float  a0 = tpA[0], a1 = tpA[1], a2 = tpA[2];
    unsigned key0[PPL];
    compute_keys(base, a0, a1, a2, a0*a0 + a1*a1 + a2*a2, lane, key0);

    unsigned key1[PPL];
    if (has2) {
        const float* tpB = tgt + ((size_t)b * NT + tq0 + 1) * 3;
        const float  c0 = tpB[0], c1 = tpB[1], c2 = tpB[2];
        compute_keys(base, c0, c1, c2, c0*c0 + c1*c1 + c2*c2, lane, key1);
    }

    // ---- select target 0 to completion ----
    SelState st0; sel_init(st0, key0);
    while (!st0.done) sel_step(st0, key0);
    const unsigned selmask0 = sel_flags(st0, key0);

    f32x4* dst0 = reinterpret_cast<f32x4*>(out + ((size_t)b * NT + tq0) * (NPTS * 3));

    if (has2) {
        // ---- fused: store row0 (VMEM) interleaved with select1 steps (VALU) ----
        SelState st1; sel_init(st1, key1);
        #pragma unroll
        for (int j = 0; j < 12; ++j) {
            store_chunk(src4, dst0, selmask0, lane, j);
            sel_step(st1, key1);
        }
        while (!st1.done) sel_step(st1, key1);
        const unsigned selmask1 = sel_flags(st1, key1);

        f32x4* dst1 = reinterpret_cast<f32x4*>(out + ((size_t)b * NT + tq0 + 1) * (NPTS * 3));
        #pragma unroll
        for (int j = 0; j < 12; ++j) store_chunk(src4, dst1, selmask1, lane, j);
    } else {
        #pragma unroll
        for (int j = 0; j < 12; ++j) store_chunk(src4, dst0, selmask0, lane, j);
    }
}

extern "C" void kernel_launch(void* const* d_in, const int* in_sizes, int n_in,
                              void* d_out, int out_size, void* d_ws, size_t ws_size,
                              hipStream_t stream) {
    const float* pc  = (const float*)d_in[0];  // (B,1024,3)
    const float* tgt = (const float*)d_in[1];  // (B,21,3)
    float*       out = (float*)d_out;          // (B,21,1024,3)

    const int B       = in_sizes[0] / (NPTS * 3);        // 512
    const int nwaves  = B * WPB;                          // 5632
    const int nblocks = (nwaves + 3) / 4;                 // 1408 (divisible by 8)

    knn_mask_paired_kernel<<<nblocks, BLOCK, 0, stream>>>(pc, tgt, out, B);
}